// Round 4
// baseline (816.979 us; speedup 1.0000x reference)
//
#include <hip/hip_runtime.h>

// ---------------------------------------------------------------------------
// VGAE encoder, MI355X. The two adj (16384x16384 f32, 1 GiB) GEMMs dominate.
// fp32 has no MFMA on CDNA4 -> split f32 into bf16 hi+lo, 3 MFMA terms
// (hi*hi + hi*lo + lo*hi), fp32 accumulate. Memory floor = 2 adj passes
// = ~340us @ 6.3 TB/s.
// R2: counted-vmcnt barriers (lgkmcnt(0)-only) + adj reg ring.
// R3: B prefetched 2 steps deep; nontemporal adj loads.       -> flat (783us)
// R4: TLP instead of mega-pipeline: 256-thread blocks, 32-row tiles,
// grid 512 = 2 independent blocks/CU so barrier convoys in one block are
// hidden by the other (m97/m102 evidence: multi-block/CU saturates HBM).
// ---------------------------------------------------------------------------

typedef __bf16 bf16_t;
typedef __attribute__((ext_vector_type(8))) __bf16 bf16x8;
typedef __attribute__((ext_vector_type(16))) float f32x16;
typedef __attribute__((ext_vector_type(4)))  float f32x4;

#define N_NODES 16384

// Fragment layout for the B operand of mfma_f32_32x32x16_bf16:
// element (k=r, col=c) -> 1KiB units indexed by (K16 = r>>4, cblk = c>>5),
// within a unit: lane = (c&31) + 32*((r>>3)&1) holds 8 bf16 (k = ..8g..8g+7).
__device__ __forceinline__ int frag_off(int r, int c) {
    int K16  = r >> 4;
    int cblk = c >> 5;
    int g    = (r >> 3) & 1;
    int lane = (c & 31) + (g << 5);
    return ((K16 * 4 + cblk) << 9) + (lane << 3) + (r & 7);
}

// ---------------------------------------------------------------------------
// Small fp32 GEMM producer: out = A[16384][K] @ W[K][128]; epilogue splits
// each output into bf16 hi/lo and scatters into the fragment layout.
// K=256 (X@W1) or K=128 (hidden@[Wm|Ws], FUSED: cols 0-63 from Wa, 64-127 Wb)
// ---------------------------------------------------------------------------
template<int K, bool FUSED>
__global__ __launch_bounds__(256)
void producer_kernel(const float* __restrict__ A,
                     const float* __restrict__ W,
                     const float* __restrict__ Wa,
                     const float* __restrict__ Wb,
                     bf16_t* __restrict__ Bh,
                     bf16_t* __restrict__ Bl)
{
    __shared__ float As[32][128];   // k-major A tile: As[k][r]
    __shared__ float Wsh[32][128];  // Wsh[k][c]
    const int t    = threadIdx.x;
    const int row0 = blockIdx.x * 128;
    const int tc   = t & 15, tr = t >> 4;   // 16x16 thread grid, 8x8 outs each

    float acc[8][8];
    #pragma unroll
    for (int i = 0; i < 8; ++i)
        #pragma unroll
        for (int j = 0; j < 8; ++j) acc[i][j] = 0.f;

    const int ra = t >> 1, ks = (t & 1) << 4;   // A staging: 16 f32/thread
    const int wk = t >> 3, wc = (t & 7) << 4;   // W staging: 16 f32/thread

    for (int k0 = 0; k0 < K; k0 += 32) {
        const float* ap = A + (size_t)(row0 + ra) * K + k0 + ks;
        float4 a0 = *(const float4*)(ap);
        float4 a1 = *(const float4*)(ap + 4);
        float4 a2 = *(const float4*)(ap + 8);
        float4 a3 = *(const float4*)(ap + 12);
        float4 w0, w1, w2, w3;
        if (!FUSED) {
            const float* wp = W + (size_t)(k0 + wk) * 128 + wc;
            w0 = *(const float4*)(wp);     w1 = *(const float4*)(wp + 4);
            w2 = *(const float4*)(wp + 8); w3 = *(const float4*)(wp + 12);
        } else {
            const float* wp = (wc < 64) ? (Wa + (size_t)(k0 + wk) * 64 + wc)
                                        : (Wb + (size_t)(k0 + wk) * 64 + (wc - 64));
            w0 = *(const float4*)(wp);     w1 = *(const float4*)(wp + 4);
            w2 = *(const float4*)(wp + 8); w3 = *(const float4*)(wp + 12);
        }
        __syncthreads();   // previous iteration's compute done before overwrite
        {
            float tmp[16] = {a0.x,a0.y,a0.z,a0.w, a1.x,a1.y,a1.z,a1.w,
                             a2.x,a2.y,a2.z,a2.w, a3.x,a3.y,a3.z,a3.w};
            #pragma unroll
            for (int j = 0; j < 16; ++j) As[ks + j][ra] = tmp[j];
            *(float4*)&Wsh[wk][wc     ] = w0;
            *(float4*)&Wsh[wk][wc +  4] = w1;
            *(float4*)&Wsh[wk][wc +  8] = w2;
            *(float4*)&Wsh[wk][wc + 12] = w3;
        }
        __syncthreads();
        #pragma unroll 4
        for (int k = 0; k < 32; ++k) {
            float av[8], wv[8];
            *(float4*)&av[0] = *(const float4*)&As[k][8 * tr];
            *(float4*)&av[4] = *(const float4*)&As[k][8 * tr + 4];
            *(float4*)&wv[0] = *(const float4*)&Wsh[k][8 * tc];
            *(float4*)&wv[4] = *(const float4*)&Wsh[k][8 * tc + 4];
            #pragma unroll
            for (int i = 0; i < 8; ++i)
                #pragma unroll
                for (int j = 0; j < 8; ++j)
                    acc[i][j] = fmaf(av[i], wv[j], acc[i][j]);
        }
    }

    #pragma unroll
    for (int i = 0; i < 8; ++i) {
        int r = row0 + 8 * tr + i;
        #pragma unroll
        for (int j = 0; j < 8; ++j) {
            int c = 8 * tc + j;
            float v = acc[i][j];
            bf16_t h = (bf16_t)v;
            bf16_t l = (bf16_t)(v - (float)h);
            int off = frag_off(r, c);
            Bh[off] = h;
            Bl[off] = l;
        }
    }
}

// ---------------------------------------------------------------------------
// Big kernel: out = act(adj @ B), M=K=16384, N=128.
// grid 512 (2 blocks/CU), 256 thr (4 waves), block tile 32x128, wave 32x32.
// Pipeline per block: B frags 2 steps deep (4 reg sets), adj 4-deep reg ring,
// loadB issued before loadA (in-order vmcnt), one raw barrier per step with
// lgkmcnt(0) only. Nontemporal adj. TLP across the 2 resident blocks hides
// the barrier convoy.
// ---------------------------------------------------------------------------
template<int ACT>  // 0=none, 1=relu
__global__ __launch_bounds__(256, 2)
void adj_gemm_kernel(const float* __restrict__ adj,
                     const bf16_t* __restrict__ Bh,
                     const bf16_t* __restrict__ Bl,
                     float* __restrict__ out)
{
    __shared__ __align__(16) bf16_t AsH[2][32 * 64];
    __shared__ __align__(16) bf16_t AsL[2][32 * 64];
    const int t    = threadIdx.x;
    const int lane = t & 63;
    const int wc   = t >> 6;                 // wave = col quadrant (0..3)
    const int row0 = blockIdx.x * 32;

    // adj staging: 8 f32/thread (row sr 0..31, k sk..sk+7)
    const int sr = t >> 3;
    const int sk = (t & 7) << 3;
    const float* aptr = adj + (size_t)(row0 + sr) * 16384 + sk;
    const int widx = ((sr << 6) + sk) ^ ((sr & 7) << 3);   // XOR swizzle (bf16 units)
    bf16_t* const wH0 = &AsH[0][widx]; bf16_t* const wH1 = &AsH[1][widx];
    bf16_t* const wL0 = &AsL[0][widx]; bf16_t* const wL1 = &AsL[1][widx];

    // A-frag read coords: row = lane&31, k = 16*s + 8*(lane>>5)
    const int frow = lane & 31;
    const int fg   = (lane >> 5) << 3;
    int ridx[4];
    #pragma unroll
    for (int s = 0; s < 4; ++s)
        ridx[s] = ((frow << 6) + (s << 4) + fg) ^ ((frow & 7) << 3);

    // B frag per-thread base (bf16 elements); step stride = 8192 elements
    const int tb = (wc << 9) + (lane << 3);

    f32x16 acc;
    #pragma unroll
    for (int i = 0; i < 16; ++i) acc[i] = 0.f;

    auto loadB = [&](bf16x8* bh, bf16x8* bl, int step) {
        const size_t base = ((size_t)step << 13) + tb;
        #pragma unroll
        for (int s = 0; s < 4; ++s) {
            bh[s] = *(const bf16x8*)(Bh + base + (s << 11));
            bl[s] = *(const bf16x8*)(Bl + base + (s << 11));
        }
    };
    auto loadA = [&](f32x4& p0, f32x4& p1, int step) {
        const f32x4* p = (const f32x4*)(aptr + (step << 6));
        p0 = __builtin_nontemporal_load(p);
        p1 = __builtin_nontemporal_load(p + 1);
    };
    auto cvtWrite = [&](const f32x4& p0, const f32x4& p1, int buf) {
        float xs[8] = {p0[0], p0[1], p0[2], p0[3], p1[0], p1[1], p1[2], p1[3]};
        bf16x8 hv, lv;
        #pragma unroll
        for (int i = 0; i < 8; ++i) {
            bf16_t h = (bf16_t)xs[i];
            hv[i] = h;
            lv[i] = (bf16_t)(xs[i] - (float)h);
        }
        *(bf16x8*)(buf ? wH1 : wH0) = hv;
        *(bf16x8*)(buf ? wL1 : wL0) = lv;
    };
    auto compute = [&](int buf, const bf16x8* bh, const bf16x8* bl) {
        #pragma unroll
        for (int s = 0; s < 4; ++s) {
            const bf16_t* baseH = buf ? &AsH[1][0] : &AsH[0][0];
            const bf16_t* baseL = buf ? &AsL[1][0] : &AsL[0][0];
            bf16x8 ah = *(const bf16x8*)(baseH + ridx[s]);
            bf16x8 al = *(const bf16x8*)(baseL + ridx[s]);
            acc = __builtin_amdgcn_mfma_f32_32x32x16_bf16(ah, bh[s], acc, 0, 0, 0);
            acc = __builtin_amdgcn_mfma_f32_32x32x16_bf16(ah, bl[s], acc, 0, 0, 0);
            acc = __builtin_amdgcn_mfma_f32_32x32x16_bf16(al, bh[s], acc, 0, 0, 0);
        }
    };

    // lgkmcnt(0)-only barrier: ds ops drained, global (register-dest) loads
    // stay in flight across the barrier (counted vmcnt by compiler).
#define SYNC_LDS() do { asm volatile("s_waitcnt lgkmcnt(0)" ::: "memory"); \
                        __builtin_amdgcn_s_barrier(); } while (0)

    f32x4 paA[4], paB[4];                        // 4-deep adj prefetch ring
    bf16x8 bhS0[4], blS0[4], bhS1[4], blS1[4];   // 4 B sets: 2-step prefetch
    bf16x8 bhS2[4], blS2[4], bhS3[4], blS3[4];

    // -------- prologue --------
    loadA(paA[0], paB[0], 0);
    loadA(paA[1], paB[1], 1);
    loadA(paA[2], paB[2], 2);
    loadA(paA[3], paB[3], 3);
    loadB(bhS0, blS0, 0);
    loadB(bhS1, blS1, 1);
    cvtWrite(paA[0], paB[0], 0);
    SYNC_LDS();

    // steady state: step i = i0 + k.  Set k&3 holds B(i); prefetch B(i+2)
    // into set (k+2)&3 FIRST (in-order vmcnt keeps 2 steps in flight); then
    // adj(i+4) into ring slot k; compute; stage adj(i+1); barrier.
#define BODY(k, CH, CL, PH, PL) do {                                        \
        loadB(PH, PL, i0 + (k) + 2);                                        \
        loadA(paA[(k)], paB[(k)], i0 + (k) + 4);                            \
        compute((k) & 1, CH, CL);                                           \
        cvtWrite(paA[((k) + 1) & 3], paB[((k) + 1) & 3], ((k) + 1) & 1);    \
        SYNC_LDS();                                                         \
    } while (0)

    for (int i0 = 0; i0 < 252; i0 += 4) {
        BODY(0, bhS0, blS0, bhS2, blS2);
        BODY(1, bhS1, blS1, bhS3, blS3);
        BODY(2, bhS2, blS2, bhS0, blS0);
        BODY(3, bhS3, blS3, bhS1, blS1);
    }
#undef BODY

    // -------- epilogue: steps 252..255 --------
    // state: S0=B252, S1=B253; ring slots 0..3 = adj 252..255; buf0 staged 252
    loadB(bhS2, blS2, 254);
    compute(0, bhS0, blS0);
    cvtWrite(paA[1], paB[1], 1);          // adj 253
    SYNC_LDS();
    loadB(bhS3, blS3, 255);
    compute(1, bhS1, blS1);
    cvtWrite(paA[2], paB[2], 0);          // adj 254
    SYNC_LDS();
    compute(0, bhS2, blS2);
    cvtWrite(paA[3], paB[3], 1);          // adj 255
    SYNC_LDS();
    compute(1, bhS3, blS3);
#undef SYNC_LDS

    // C write: col = lane&31 (+32*wc), row = (q&3) + 8*(q>>2) + 4*(lane>>5)
    const int col = (wc << 5) + (lane & 31);
    const int rb  = row0 + ((lane >> 5) << 2);
    #pragma unroll
    for (int q = 0; q < 16; ++q) {
        int r = rb + (q & 3) + ((q >> 2) << 3);
        float v = acc[q];
        if (ACT == 1) v = fmaxf(v, 0.f);
        out[(size_t)r * 128 + col] = v;
    }
}

// ---------------------------------------------------------------------------
// Final: mean = Z@Wp + bp; out = noise*exp(min(logstd,10)) + mean
// T = [Z | logstd] as [16384][128] f32
// ---------------------------------------------------------------------------
__global__ __launch_bounds__(256)
void final_kernel(const float* __restrict__ T,
                  const float* __restrict__ Wp,
                  const float* __restrict__ bp,
                  const float* __restrict__ noise,
                  float* __restrict__ out)
{
    __shared__ float Wps[64][64];
    __shared__ float Ts[64][64];
    const int t = threadIdx.x;
    const int row0 = blockIdx.x * 64;
    {
        int k = t >> 2, c0 = (t & 3) << 4;
        #pragma unroll
        for (int i = 0; i < 4; ++i)
            *(float4*)&Wps[k][c0 + 4 * i] = *(const float4*)&Wp[(size_t)k * 64 + c0 + 4 * i];
        #pragma unroll
        for (int i = 0; i < 4; ++i)
            *(float4*)&Ts[k][c0 + 4 * i] =
                *(const float4*)&T[(size_t)(row0 + k) * 128 + c0 + 4 * i];
    }
    __syncthreads();

    const int r  = t >> 2;
    const int c0 = (t & 3) << 4;
    float acc[16];
    #pragma unroll
    for (int j = 0; j < 16; ++j) acc[j] = bp[c0 + j];
    for (int k = 0; k < 64; ++k) {
        float a = Ts[r][k];
        #pragma unroll
        for (int j = 0; j < 16; ++j) acc[j] = fmaf(a, Wps[k][c0 + j], acc[j]);
    }
    const int grow = row0 + r;
    #pragma unroll
    for (int j = 0; j < 16; ++j) {
        float ls = T[(size_t)grow * 128 + 64 + c0 + j];
        ls = fminf(ls, 10.0f);
        out[(size_t)grow * 64 + c0 + j] =
            noise[(size_t)grow * 64 + c0 + j] * __expf(ls) + acc[j];
    }
}

// ---------------------------------------------------------------------------
extern "C" void kernel_launch(void* const* d_in, const int* in_sizes, int n_in,
                              void* d_out, int out_size, void* d_ws, size_t ws_size,
                              hipStream_t stream) {
    const float* X     = (const float*)d_in[0];
    const float* adj   = (const float*)d_in[1];
    const float* W1    = (const float*)d_in[2];
    const float* Wm    = (const float*)d_in[3];
    const float* Wsv   = (const float*)d_in[4];
    const float* Wp    = (const float*)d_in[5];
    const float* bp    = (const float*)d_in[6];
    const float* noise = (const float*)d_in[7];
    float* out = (float*)d_out;

    char* ws = (char*)d_ws;
    bf16_t* Bh   = (bf16_t*)ws;                    // 4 MB  (16384*128 bf16)
    bf16_t* Bl   = (bf16_t*)(ws + (4u << 20));     // 4 MB
    float*  Htmp = (float*)(ws + (8u << 20));      // 8 MB hidden, reused as T

    // S1: B1 = fragsplit((X @ W1)^T)
    producer_kernel<256, false><<<128, 256, 0, stream>>>(X, W1, nullptr, nullptr, Bh, Bl);
    // S2: hidden = relu(adj @ XW1)
    adj_gemm_kernel<1><<<512, 256, 0, stream>>>(adj, Bh, Bl, Htmp);
    // S3: B2 = fragsplit((hidden @ [Wm|Ws])^T)
    producer_kernel<128, true><<<128, 256, 0, stream>>>(Htmp, nullptr, Wm, Wsv, Bh, Bl);
    // S4: T = adj @ HW   (cols 0-63 = Z, 64-127 = logstd_raw)
    adj_gemm_kernel<0><<<512, 256, 0, stream>>>(adj, Bh, Bl, Htmp);
    // S5: epilogue
    final_kernel<<<256, 256, 0, stream>>>(Htmp, Wp, bp, noise, out);
}

// Round 5
// 724.628 us; speedup vs baseline: 1.1274x; 1.1274x over previous
//
#include <hip/hip_runtime.h>

// ---------------------------------------------------------------------------
// VGAE encoder, MI355X. The two adj (16384x16384 f32, 1 GiB) GEMMs dominate.
// fp32 has no MFMA on CDNA4 -> split f32 into bf16 hi+lo, 3 MFMA terms
// (hi*hi + hi*lo + lo*hi), fp32 accumulate. Floor = 2 adj passes ~340us.
// R2: counted-vmcnt barriers + reg rings.                (796us)
// R3: deeper B prefetch, nontemporal adj.                (783us, flat)
// R4: 2 blocks/CU TLP.                                   (817us, worse)
// R5: DRAM-granularity theory: 256-B/row/step streaming hits the activate-
// rate wall (~2.8 TB/s). Stage K=256 per LDS buffer ([2][64][256] hi+lo =
// 128KB), adj read as 1-KB-contiguous wave bursts (1 inst = 1 row-chunk),
// barrier per MACRO step (4 sub-phases), B 2 sub-phases deep.
// ---------------------------------------------------------------------------

typedef __bf16 bf16_t;
typedef __attribute__((ext_vector_type(4))) __bf16 bf16x4;
typedef __attribute__((ext_vector_type(8))) __bf16 bf16x8;
typedef __attribute__((ext_vector_type(16))) float f32x16;
typedef __attribute__((ext_vector_type(4)))  float f32x4;

#define N_NODES 16384

// Fragment layout for the B operand of mfma_f32_32x32x16_bf16:
// element (k=r, col=c) -> 1KiB units indexed by (K16 = r>>4, cblk = c>>5),
// within a unit: lane = (c&31) + 32*((r>>3)&1) holds 8 bf16 (k = ..8g..8g+7).
__device__ __forceinline__ int frag_off(int r, int c) {
    int K16  = r >> 4;
    int cblk = c >> 5;
    int g    = (r >> 3) & 1;
    int lane = (c & 31) + (g << 5);
    return ((K16 * 4 + cblk) << 9) + (lane << 3) + (r & 7);
}

// ---------------------------------------------------------------------------
// Small fp32 GEMM producer: out = A[16384][K] @ W[K][128]; epilogue splits
// each output into bf16 hi/lo and scatters into the fragment layout.
// ---------------------------------------------------------------------------
template<int K, bool FUSED>
__global__ __launch_bounds__(256)
void producer_kernel(const float* __restrict__ A,
                     const float* __restrict__ W,
                     const float* __restrict__ Wa,
                     const float* __restrict__ Wb,
                     bf16_t* __restrict__ Bh,
                     bf16_t* __restrict__ Bl)
{
    __shared__ float As[32][128];   // k-major A tile: As[k][r]
    __shared__ float Wsh[32][128];  // Wsh[k][c]
    const int t    = threadIdx.x;
    const int row0 = blockIdx.x * 128;
    const int tc   = t & 15, tr = t >> 4;   // 16x16 thread grid, 8x8 outs each

    float acc[8][8];
    #pragma unroll
    for (int i = 0; i < 8; ++i)
        #pragma unroll
        for (int j = 0; j < 8; ++j) acc[i][j] = 0.f;

    const int ra = t >> 1, ks = (t & 1) << 4;   // A staging: 16 f32/thread
    const int wk = t >> 3, wc = (t & 7) << 4;   // W staging: 16 f32/thread

    for (int k0 = 0; k0 < K; k0 += 32) {
        const float* ap = A + (size_t)(row0 + ra) * K + k0 + ks;
        float4 a0 = *(const float4*)(ap);
        float4 a1 = *(const float4*)(ap + 4);
        float4 a2 = *(const float4*)(ap + 8);
        float4 a3 = *(const float4*)(ap + 12);
        float4 w0, w1, w2, w3;
        if (!FUSED) {
            const float* wp = W + (size_t)(k0 + wk) * 128 + wc;
            w0 = *(const float4*)(wp);     w1 = *(const float4*)(wp + 4);
            w2 = *(const float4*)(wp + 8); w3 = *(const float4*)(wp + 12);
        } else {
            const float* wp = (wc < 64) ? (Wa + (size_t)(k0 + wk) * 64 + wc)
                                        : (Wb + (size_t)(k0 + wk) * 64 + (wc - 64));
            w0 = *(const float4*)(wp);     w1 = *(const float4*)(wp + 4);
            w2 = *(const float4*)(wp + 8); w3 = *(const float4*)(wp + 12);
        }
        __syncthreads();   // previous iteration's compute done before overwrite
        {
            float tmp[16] = {a0.x,a0.y,a0.z,a0.w, a1.x,a1.y,a1.z,a1.w,
                             a2.x,a2.y,a2.z,a2.w, a3.x,a3.y,a3.z,a3.w};
            #pragma unroll
            for (int j = 0; j < 16; ++j) As[ks + j][ra] = tmp[j];
            *(float4*)&Wsh[wk][wc     ] = w0;
            *(float4*)&Wsh[wk][wc +  4] = w1;
            *(float4*)&Wsh[wk][wc +  8] = w2;
            *(float4*)&Wsh[wk][wc + 12] = w3;
        }
        __syncthreads();
        #pragma unroll 4
        for (int k = 0; k < 32; ++k) {
            float av[8], wv[8];
            *(float4*)&av[0] = *(const float4*)&As[k][8 * tr];
            *(float4*)&av[4] = *(const float4*)&As[k][8 * tr + 4];
            *(float4*)&wv[0] = *(const float4*)&Wsh[k][8 * tc];
            *(float4*)&wv[4] = *(const float4*)&Wsh[k][8 * tc + 4];
            #pragma unroll
            for (int i = 0; i < 8; ++i)
                #pragma unroll
                for (int j = 0; j < 8; ++j)
                    acc[i][j] = fmaf(av[i], wv[j], acc[i][j]);
        }
    }

    #pragma unroll
    for (int i = 0; i < 8; ++i) {
        int r = row0 + 8 * tr + i;
        #pragma unroll
        for (int j = 0; j < 8; ++j) {
            int c = 8 * tc + j;
            float v = acc[i][j];
            bf16_t h = (bf16_t)v;
            bf16_t l = (bf16_t)(v - (float)h);
            int off = frag_off(r, c);
            Bh[off] = h;
            Bl[off] = l;
        }
    }
}

// ---------------------------------------------------------------------------
// Big kernel: out = act(adj @ B), M=K=16384, N=128.
// grid 256 (1 block/CU), 512 thr (8 waves 2x4), block tile 64x128.
// Macro-step K=256: LDS [2][64][256] hi+lo bf16 (128KB). adj staged as 1-KB
// contiguous wave bursts (wave w reads rows w*8..w*8+7, one f32x4-inst per
// row). 4 compute sub-phases (K=64) per macro; ONE lgkmcnt-only barrier per
// macro. B frags direct L2->reg, 2 sub-phases deep (4 reg sets).
// LDS layout: elem (row,c) at idx row*256 + (c ^ ((row&7)<<3)).
// ---------------------------------------------------------------------------
template<int ACT>  // 0=none, 1=relu
__global__ __launch_bounds__(512, 2)
void adj_gemm_kernel(const float* __restrict__ adj,
                     const bf16_t* __restrict__ Bh,
                     const bf16_t* __restrict__ Bl,
                     float* __restrict__ out)
{
    __shared__ __align__(16) bf16_t AsH[2][64 * 256];
    __shared__ __align__(16) bf16_t AsL[2][64 * 256];
    const int t    = threadIdx.x;
    const int lane = t & 63;
    const int w    = t >> 6;
    const int wr   = w >> 2, wc = w & 3;     // 2x4 wave grid
    const int row0 = blockIdx.x * 64;

    // adj staging: wave w stages rows w*8..w*8+7; per row one wave-wide
    // f32x4 burst (64 lanes x 16B = 1KB contiguous)
    const float* aBase = adj + (size_t)(row0 + w * 8) * 16384 + lane * 4;

    // A-frag read coords: row = 32*wr + (lane&31), k = 16*s + 8*(lane>>5)
    const int frow = (wr << 5) + (lane & 31);
    const int fg   = (lane >> 5) << 3;
    const int rswz = (frow & 7) << 3;
    const int rbase = frow << 8;

    // B frag per-thread base (bf16 elements); sub-phase stride = 8192 elems
    const int tb = (wc << 9) + (lane << 3);

    f32x16 acc;
    #pragma unroll
    for (int i = 0; i < 16; ++i) acc[i] = 0.f;

    f32x4 ar[8];   // one macro-step of adj rows (literal-indexed only)

    auto loadAdj = [&](int mac) {
        const float* p = aBase + (mac << 8);
        ar[0] = __builtin_nontemporal_load((const f32x4*)(p));
        ar[1] = __builtin_nontemporal_load((const f32x4*)(p + 16384));
        ar[2] = __builtin_nontemporal_load((const f32x4*)(p + 2 * 16384));
        ar[3] = __builtin_nontemporal_load((const f32x4*)(p + 3 * 16384));
        ar[4] = __builtin_nontemporal_load((const f32x4*)(p + 4 * 16384));
        ar[5] = __builtin_nontemporal_load((const f32x4*)(p + 5 * 16384));
        ar[6] = __builtin_nontemporal_load((const f32x4*)(p + 6 * 16384));
        ar[7] = __builtin_nontemporal_load((const f32x4*)(p + 7 * 16384));
    };
    auto cvtWrite = [&](int buf) {
        #pragma unroll
        for (int j = 0; j < 8; ++j) {
            bf16x4 hv, lv;
            #pragma unroll
            for (int e = 0; e < 4; ++e) {
                float v = ar[j][e];
                bf16_t h = (bf16_t)v;
                hv[e] = h;
                lv[e] = (bf16_t)(v - (float)h);
            }
            int idx = (((w << 3) + j) << 8) + ((lane << 2) ^ (j << 3));
            *(bf16x4*)&AsH[buf][idx] = hv;
            *(bf16x4*)&AsL[buf][idx] = lv;
        }
    };
    auto loadB = [&](bf16x8* bh, bf16x8* bl, int sub) {
        const size_t base = ((size_t)sub << 13) + tb;
        #pragma unroll
        for (int s = 0; s < 4; ++s) {
            bh[s] = *(const bf16x8*)(Bh + base + (s << 11));
            bl[s] = *(const bf16x8*)(Bl + base + (s << 11));
        }
    };
    auto compute = [&](int buf, const bf16x8* bh, const bf16x8* bl, int sbase) {
        #pragma unroll
        for (int s = 0; s < 4; ++s) {
            int idx = rbase + ((((sbase + s) << 4) + fg) ^ rswz);
            bf16x8 ah = *(const bf16x8*)&AsH[buf][idx];
            bf16x8 al = *(const bf16x8*)&AsL[buf][idx];
            acc = __builtin_amdgcn_mfma_f32_32x32x16_bf16(ah, bh[s], acc, 0, 0, 0);
            acc = __builtin_amdgcn_mfma_f32_32x32x16_bf16(ah, bl[s], acc, 0, 0, 0);
            acc = __builtin_amdgcn_mfma_f32_32x32x16_bf16(al, bh[s], acc, 0, 0, 0);
        }
    };

    // lgkmcnt(0)-only barrier: ds ops drained; global register-dest loads
    // stay in flight across the barrier (counted vmcnt by compiler).
#define SYNC_LDS() do { asm volatile("s_waitcnt lgkmcnt(0)" ::: "memory"); \
                        __builtin_amdgcn_s_barrier(); } while (0)

    bf16x8 bhS0[4], blS0[4], bhS1[4], blS1[4];   // 4 B sets: 2-sub-phase deep
    bf16x8 bhS2[4], blS2[4], bhS3[4], blS3[4];

    // -------- prologue --------
    loadAdj(0);
    cvtWrite(0);
    loadB(bhS0, blS0, 0);
    loadB(bhS1, blS1, 1);
    SYNC_LDS();
    loadAdj(1);

    // 64 macro-steps of K=256; macro m uses buf m&1; subs 4m..4m+3.
    // Entering macro m: S0=B(4m), S1=B(4m+1).
    for (int m = 0; m < 63; ++m) {
        const int buf = m & 1;
        const int s4 = m << 2;
        loadB(bhS2, blS2, s4 + 2);
        compute(buf, bhS0, blS0, 0);
        loadB(bhS3, blS3, s4 + 3);
        compute(buf, bhS1, blS1, 4);
        loadB(bhS0, blS0, s4 + 4);
        cvtWrite(buf ^ 1);                  // stage macro m+1 (waits adj regs)
        compute(buf, bhS2, blS2, 8);
        loadB(bhS1, blS1, s4 + 5);
        compute(buf, bhS3, blS3, 12);
        SYNC_LDS();
        if (m < 62) loadAdj(m + 2);
    }
    // -------- epilogue macro m=63 (buf 1): S0=B(252), S1=B(253) --------
    loadB(bhS2, blS2, 254);
    compute(1, bhS0, blS0, 0);
    loadB(bhS3, blS3, 255);
    compute(1, bhS1, blS1, 4);
    compute(1, bhS2, blS2, 8);
    compute(1, bhS3, blS3, 12);
#undef SYNC_LDS

    // C write: col = lane&31 (+32*wc), row = (q&3) + 8*(q>>2) + 4*(lane>>5)
    const int col = (wc << 5) + (lane & 31);
    const int rb  = row0 + (wr << 5) + ((lane >> 5) << 2);
    #pragma unroll
    for (int q = 0; q < 16; ++q) {
        int r = rb + (q & 3) + ((q >> 2) << 3);
        float v = acc[q];
        if (ACT == 1) v = fmaxf(v, 0.f);
        out[(size_t)r * 128 + col] = v;
    }
}

// ---------------------------------------------------------------------------
// Final: mean = Z@Wp + bp; out = noise*exp(min(logstd,10)) + mean
// T = [Z | logstd] as [16384][128] f32
// ---------------------------------------------------------------------------
__global__ __launch_bounds__(256)
void final_kernel(const float* __restrict__ T,
                  const float* __restrict__ Wp,
                  const float* __restrict__ bp,
                  const float* __restrict__ noise,
                  float* __restrict__ out)
{
    __shared__ float Wps[64][64];
    __shared__ float Ts[64][64];
    const int t = threadIdx.x;
    const int row0 = blockIdx.x * 64;
    {
        int k = t >> 2, c0 = (t & 3) << 4;
        #pragma unroll
        for (int i = 0; i < 4; ++i)
            *(float4*)&Wps[k][c0 + 4 * i] = *(const float4*)&Wp[(size_t)k * 64 + c0 + 4 * i];
        #pragma unroll
        for (int i = 0; i < 4; ++i)
            *(float4*)&Ts[k][c0 + 4 * i] =
                *(const float4*)&T[(size_t)(row0 + k) * 128 + c0 + 4 * i];
    }
    __syncthreads();

    const int r  = t >> 2;
    const int c0 = (t & 3) << 4;
    float acc[16];
    #pragma unroll
    for (int j = 0; j < 16; ++j) acc[j] = bp[c0 + j];
    for (int k = 0; k < 64; ++k) {
        float a = Ts[r][k];
        #pragma unroll
        for (int j = 0; j < 16; ++j) acc[j] = fmaf(a, Wps[k][c0 + j], acc[j]);
    }
    const int grow = row0 + r;
    #pragma unroll
    for (int j = 0; j < 16; ++j) {
        float ls = T[(size_t)grow * 128 + 64 + c0 + j];
        ls = fminf(ls, 10.0f);
        out[(size_t)grow * 64 + c0 + j] =
            noise[(size_t)grow * 64 + c0 + j] * __expf(ls) + acc[j];
    }
}

// ---------------------------------------------------------------------------
extern "C" void kernel_launch(void* const* d_in, const int* in_sizes, int n_in,
                              void* d_out, int out_size, void* d_ws, size_t ws_size,
                              hipStream_t stream) {
    const float* X     = (const float*)d_in[0];
    const float* adj   = (const float*)d_in[1];
    const float* W1    = (const float*)d_in[2];
    const float* Wm    = (const float*)d_in[3];
    const float* Wsv   = (const float*)d_in[4];
    const float* Wp    = (const float*)d_in[5];
    const float* bp    = (const float*)d_in[6];
    const float* noise = (const float*)d_in[7];
    float* out = (float*)d_out;

    char* ws = (char*)d_ws;
    bf16_t* Bh   = (bf16_t*)ws;                    // 4 MB  (16384*128 bf16)
    bf16_t* Bl   = (bf16_t*)(ws + (4u << 20));     // 4 MB
    float*  Htmp = (float*)(ws + (8u << 20));      // 8 MB hidden, reused as T

    // S1: B1 = fragsplit((X @ W1)^T)
    producer_kernel<256, false><<<128, 256, 0, stream>>>(X, W1, nullptr, nullptr, Bh, Bl);
    // S2: hidden = relu(adj @ XW1)
    adj_gemm_kernel<1><<<256, 512, 0, stream>>>(adj, Bh, Bl, Htmp);
    // S3: B2 = fragsplit((hidden @ [Wm|Ws])^T)
    producer_kernel<128, true><<<128, 256, 0, stream>>>(Htmp, nullptr, Wm, Wsv, Bh, Bl);
    // S4: T = adj @ HW   (cols 0-63 = Z, 64-127 = logstd_raw)
    adj_gemm_kernel<0><<<256, 512, 0, stream>>>(adj, Bh, Bl, Htmp);
    // S5: epilogue
    final_kernel<<<256, 256, 0, stream>>>(Htmp, Wp, bp, noise, out);
}